// Round 15
// baseline (459.135 us; speedup 1.0000x reference)
//
#include <hip/hip_runtime.h>
#include <hip/hip_bf16.h>
#include <stdint.h>

// MoE top-1. Round 15: wtrans weights -> bf16 [N][K]; grouped GEMMs use the
// m201-style phase-split schedule: BM256/BN128/BK64, 8 waves, triple-buffered
// LDS (144KB), both operands via global_load_lds, counted vmcnt(6) per group
// (never drained in steady state), setprio around MFMA clusters.
#define N_TOK 4096
#define DIM   768
#define NE    8
#define HDIM  7680
#define ODIM  768
#define G1GRID 1536   // 8 XCDs x 192 slots
#define G2GRID 768    // 8 XCDs x 96 slots

typedef __bf16 bf16x8 __attribute__((ext_vector_type(8)));
typedef float f32x4 __attribute__((ext_vector_type(4)));

__device__ __forceinline__ unsigned short f2bf(float f) {
    union { float f; unsigned u; } v; v.f = f;
    return (unsigned short)((v.u + 0x7fffu + ((v.u >> 16) & 1u)) >> 16);
}

__device__ __forceinline__ void gload_lds16(const unsigned short* g, unsigned short* l) {
    __builtin_amdgcn_global_load_lds(
        (const __attribute__((address_space(1))) unsigned int*)g,
        (__attribute__((address_space(3))) unsigned int*)l, 16, 0, 0);
}

// ---------------- gating & prep (validated rounds 1-14) ----------------
__global__ void moe_gating(const float* __restrict__ x, const float* __restrict__ Wg,
                           const float* __restrict__ bg, int* __restrict__ cnt,
                           int* __restrict__ top_e, int* __restrict__ rnk,
                           float* __restrict__ top_p) {
    const int wid  = threadIdx.x >> 6;
    const int lane = threadIdx.x & 63;
    const int t = blockIdx.x * 4 + wid;
    double p[NE];
#pragma unroll
    for (int j = 0; j < NE; ++j) p[j] = 0.0;
    const float* xr  = x  + (size_t)t * DIM + lane * 12;
    const float* wr0 = Wg + lane * 12 * NE;
#pragma unroll
    for (int i = 0; i < 12; ++i) {
        double xv = (double)xr[i];
#pragma unroll
        for (int j = 0; j < NE; ++j) p[j] += xv * (double)wr0[i * NE + j];
    }
#pragma unroll
    for (int off = 32; off >= 1; off >>= 1)
#pragma unroll
        for (int j = 0; j < NE; ++j) p[j] += __shfl_xor(p[j], off, 64);
    if (lane == 0) {
        double l[NE];
#pragma unroll
        for (int j = 0; j < NE; ++j) l[j] = p[j] + (double)bg[j];
        int be = 0; double bl = l[0];
#pragma unroll
        for (int j = 1; j < NE; ++j) if (l[j] > bl) { bl = l[j]; be = j; }
        double s = 0.0;
#pragma unroll
        for (int j = 0; j < NE; ++j) s += exp(l[j] - bl);
        int rk = atomicAdd(&cnt[be], 1);
        top_e[t] = be; rnk[t] = rk; top_p[t] = (float)(1.0 / s);
    }
}

__global__ void moe_init(int* cnt) { if (threadIdx.x < NE) cnt[threadIdx.x] = 0; }

// mc[e] = ceil(cnt/256) (256-row m-tiles). G1: 480 groups (e,n0 of 60);
// G2: 48 groups (e,n0 of 6), members ks-major. Group p -> XCD p%8. (r12)
__global__ void moe_scan(const int* __restrict__ cnt, int* __restrict__ offs,
                         int* __restrict__ mc, int* __restrict__ g1s,
                         int* __restrict__ g2s) {
    __shared__ int smc[NE];
    int tid = threadIdx.x;
    if (tid == 0) { int s = 0; for (int e = 0; e < NE; ++e) { offs[e] = s; s += cnt[e]; } }
    if (tid < NE) { smc[tid] = (cnt[tid] + 255) >> 8; mc[tid] = smc[tid]; }
    __syncthreads();
    if (tid < 8) {
        int s = 0;
        for (int j = 0; j < 60; ++j) { int p = tid + 8 * j; g1s[p] = s; s += smc[p / 60]; }
        int s2 = 0;
        for (int j = 0; j < 6; ++j)  { int p = tid + 8 * j; g2s[p] = s2; s2 += 4 * smc[p / 6]; }
    }
}

__global__ void moe_fill(const int* __restrict__ mc, const int* __restrict__ g1s,
                         const int* __restrict__ g2s, int* __restrict__ tbl1,
                         int* __restrict__ tbl2) {
    int gid = blockIdx.x * 256 + threadIdx.x;
    if (gid < G1GRID) {
        int c = gid & 7, slot = gid >> 3;
        int sel = c;
        for (int j = 0; j < 60; ++j) { int p = c + 8 * j; if (g1s[p] <= slot) sel = p; else break; }
        int e = sel / 60, n0 = sel % 60;
        int mt = slot - g1s[sel];
        tbl1[gid] = (mt < mc[e]) ? ((e << 14) | (mt << 8) | (n0 << 2)) : -1;
    } else if (gid < G1GRID + G2GRID) {
        int gg = gid - G1GRID;
        int c = gg & 7, slot = gg >> 3;
        int sel = c;
        for (int j = 0; j < 6; ++j) { int p = c + 8 * j; if (g2s[p] <= slot) sel = p; else break; }
        int e = sel / 6, n0 = sel % 6;
        int mem = slot - g2s[sel];
        int mcE = mc[e];
        int ks = mem / mcE, mt = mem - ks * mcE;
        tbl2[gg] = (mem < 4 * mcE) ? ((e << 14) | (mt << 8) | (n0 << 2) | ks) : -1;
    }
}

__global__ void moe_mkperm(const int* __restrict__ top_e, const int* __restrict__ rnk,
                           const float* __restrict__ top_p, const int* __restrict__ offs,
                           int* __restrict__ perm, float* __restrict__ gate_s) {
    int t = blockIdx.x * 256 + threadIdx.x;
    int e = top_e[t];
    int slot = offs[e] + rnk[t];
    perm[slot] = t;
    gate_s[slot] = top_p[t];
}

__global__ void moe_gather(const float* __restrict__ x, const int* __restrict__ perm,
                           unsigned short* __restrict__ Xg) {
    int slot = blockIdx.x;
    int t = perm[slot];
    const float* src = x + (size_t)t * DIM;
    unsigned short* dst = Xg + (size_t)slot * DIM;
    for (int i = threadIdx.x; i < DIM; i += 256) dst[i] = f2bf(src[i]);
}

__global__ void moe_initout(const int* __restrict__ top_e, const float* __restrict__ top_p,
                            const float* __restrict__ b2, float* __restrict__ out) {
    int t = blockIdx.x;
    int e = top_e[t];
    float gv = top_p[t];
    const float* b = b2 + (size_t)e * ODIM;
    float* o = out + (size_t)t * ODIM;
    for (int i = threadIdx.x; i < ODIM; i += 256) o[i] = gv * b[i];
}

// ------- weight transpose-convert: fp32 [K][N] -> bf16 [N][K] (r8, validated) -------
__global__ __launch_bounds__(256) void moe_wtrans(const float* __restrict__ in,
                                                  unsigned short* __restrict__ outw,
                                                  int K, int N) {
    __shared__ __align__(16) unsigned short t[64][72];
    const int tid = threadIdx.x;
    const float* src = in + (size_t)blockIdx.z * K * N + (size_t)(blockIdx.y * 64) * N
                          + blockIdx.x * 64;
    unsigned short* dst = outw + (size_t)blockIdx.z * K * N + (size_t)(blockIdx.x * 64) * K
                               + blockIdx.y * 64;
    const int kr = tid >> 4;
    const int nc = (tid & 15) * 4;
#pragma unroll
    for (int p = 0; p < 4; ++p) {
        float4 v = *(const float4*)(src + (size_t)(p * 16 + kr) * N + nc);
        t[nc + 0][p * 16 + kr] = f2bf(v.x);
        t[nc + 1][p * 16 + kr] = f2bf(v.y);
        t[nc + 2][p * 16 + kr] = f2bf(v.z);
        t[nc + 3][p * 16 + kr] = f2bf(v.w);
    }
    __syncthreads();
    const int nr = tid >> 3;
    const int kc = (tid & 7) * 8;
#pragma unroll
    for (int p = 0; p < 2; ++p) {
        uint4 q = *(const uint4*)&t[p * 32 + nr][kc];
        *(uint4*)(dst + (size_t)(p * 32 + nr) * K + kc) = q;
    }
}

// ---------------- phase-split grouped GEMM ----------------
// BM=256, BN=128, BK=64. 512 thr / 8 waves (4M x 2N), wave tile 64x64,
// acc[4][4] (64 AGPR). LDS: 3 tile-slots x (A 32KB + B 16KB) = 144KB,
// fragment-ordered cells [cell=(mf|nf)*2+kk][lane*8] -> lane-linear b128
// reads, 0 conflicts; gload_lds sources carry the layout permutation.
// Per K-tile: 2 phases {8 ds_read; issue 3 stage loads; barrier; lgkmcnt(0);
// setprio(1); 16 MFMA; setprio(0); [vmcnt(6) @ group end]; barrier}.
// Slot rotation: group t reads slot t%3, stages tile t+2 into (t+2)%3
// (freed at end of group t-1). vmcnt(6) retires exactly the prior group's
// 6 loads; this group's 6 stay in flight -> ~2 K-tiles of latency cover.
template<int LAYER>
__global__ __launch_bounds__(512, 1) void moe_gemm8(
    const unsigned short* __restrict__ A, const unsigned short* __restrict__ Wt,
    const float* __restrict__ bias, const int* __restrict__ cnt,
    const int* __restrict__ offs, const int* __restrict__ perm,
    const float* __restrict__ gate_s, const int* __restrict__ tbl,
    unsigned short* __restrict__ H, float* __restrict__ out) {

    constexpr int NT    = (LAYER == 1) ? HDIM : ODIM;
    constexpr int AST   = (LAYER == 1) ? DIM  : HDIM;
    constexpr int KFULL = (LAYER == 1) ? DIM  : HDIM;
    constexpr int KBLK  = (LAYER == 1) ? DIM  : HDIM / 4;
    constexpr int NITER = KBLK / 64;              // 12 / 30

    const int code = tbl[blockIdx.x];
    if (code < 0) return;
    const int e  = code >> 14;
    const int mt = (code >> 8) & 63;
    const int n0 = ((code >> 2) & 63) * 128;
    const int ks = code & 3;
    const int ne = cnt[e];
    const int base = offs[e];
    const int mlim = ne - mt * 256;
    const int kbase = ks * KBLK;

    __shared__ __align__(16) unsigned short L[73728];   // 144 KB

    const int tid = threadIdx.x;
    const int lane = tid & 63, w = tid >> 6;            // w 0..7
    const int wr = w >> 1, wc = w & 1;                  // 4(M) x 2(N)
    const int g = lane >> 4, r = lane & 15;

    // A staging: thread covers rows w*32+r and w*32+16+r (clamped)
    const int rA0 = w * 32 + r, rA1 = rA0 + 16;
    const int cA0 = rA0 < mlim ? rA0 : mlim - 1;
    const int cA1 = rA1 < mlim ? rA1 : mlim - 1;
    const unsigned short* aS0 = A + (size_t)(base + mt * 256 + cA0) * AST + kbase + g * 8;
    const unsigned short* aS1 = A + (size_t)(base + mt * 256 + cA1) * AST + kbase + g * 8;
    // B staging: thread covers weight row n = n0 + w*16 + r
    const unsigned short* bSp = Wt + (size_t)e * NT * KFULL
                                + (size_t)(n0 + w * 16 + r) * KFULL + kbase + g * 8;
    const int adc = w * 4;                              // A cells w*4..+3
    const int bdc = w * 2;                              // B cells w*2..+1

    f32x4 acc[4][4] = {};

// stage half (kk_) of tile t2_ into slot base ssb_: 3 gload_lds / thread
#define STG(t2_, ssb_, kk_)                                                    \
    do { int ko_ = (t2_) * 64 + (kk_) * 32;                                    \
        gload_lds16(aS0 + ko_, &L[(ssb_) + (adc + 0 + (kk_)) * 512]);          \
        gload_lds16(aS1 + ko_, &L[(ssb_) + (adc + 2 + (kk_)) * 512]);          \
        gload_lds16(bSp + ko_, &L[(ssb_) + 16384 + (bdc + (kk_)) * 512]);      \
    } while (0)

// one phase: ds_read frags(kk_) of slot rb_, optional stage, barrier,
// lgkm-drain, prio-wrapped 16 MFMA, optional vmcnt, optional barrier.
#define PHASE(rb_, kk_, doSTG_, t2_, ssb_, VM_, doBAR_)                        \
    do {                                                                       \
        bf16x8 af_[4], bf_[4];                                                 \
        _Pragma("unroll")                                                      \
        for (int m_ = 0; m_ < 4; ++m_)                                         \
            af_[m_] = *(const bf16x8*)&L[(rb_) + ((wr * 4 + m_) * 2 + (kk_)) * 512 + lane * 8]; \
        _Pragma("unroll")                                                      \
        for (int n_ = 0; n_ < 4; ++n_)                                         \
            bf_[n_] = *(const bf16x8*)&L[(rb_) + 16384 + ((wc * 4 + n_) * 2 + (kk_)) * 512 + lane * 8]; \
        if (doSTG_) STG(t2_, ssb_, kk_);                                       \
        __builtin_amdgcn_s_barrier();                                          \
        asm volatile("s_waitcnt lgkmcnt(0)" ::: "memory");                     \
        __builtin_amdgcn_sched_barrier(0);                                     \
        __builtin_amdgcn_s_setprio(1);                                         \
        _Pragma("unroll")                                                      \
        for (int n_ = 0; n_ < 4; ++n_)                                         \
            _Pragma("unroll")                                                  \
            for (int m_ = 0; m_ < 4; ++m_)                                     \
                acc[m_][n_] = __builtin_amdgcn_mfma_f32_16x16x32_bf16(         \
                    af_[m_], bf_[n_], acc[m_][n_], 0, 0, 0);                   \
        __builtin_amdgcn_s_setprio(0);                                         \
        if ((VM_) == 1) asm volatile("s_waitcnt vmcnt(6)" ::: "memory");       \
        else if ((VM_) == 2) asm volatile("s_waitcnt vmcnt(0)" ::: "memory");  \
        if (doBAR_) __builtin_amdgcn_s_barrier();                              \
    } while (0)

    // prologue: stage tiles 0,1 (12 loads); tile 0 landed after vmcnt(6)
    STG(0, 0, 0); STG(0, 0, 1);
    STG(1, 24576, 0); STG(1, 24576, 1);
    asm volatile("s_waitcnt vmcnt(6)" ::: "memory");
    __builtin_amdgcn_s_barrier();
    __builtin_amdgcn_sched_barrier(0);

    int b0 = 0, b1 = 24576, b2 = 49152;
#pragma unroll 1
    for (int t = 0; t < NITER; ++t) {
        const bool stg = (t < NITER - 2);
        PHASE(b0, 0, stg, t + 2, b2, 0, 1);
        const int vm = stg ? 1 : ((t == NITER - 2) ? 2 : 0);
        PHASE(b0, 1, stg, t + 2, b2, vm, (t < NITER - 1) ? 1 : 0);
        int tmp = b0; b0 = b1; b1 = b2; b2 = tmp;
    }

#undef PHASE
#undef STG

    // epilogue: C/D layout col = lane&15 (=r), row = 4*(lane>>4) (=4g) + reg
#pragma unroll
    for (int m = 0; m < 4; ++m) {
#pragma unroll
        for (int j = 0; j < 4; ++j) {
            int lrow = mt * 256 + wr * 64 + m * 16 + g * 4 + j;
            if (lrow < ne) {
                int slot = base + lrow;
#pragma unroll
                for (int n = 0; n < 4; ++n) {
                    int col = n0 + wc * 64 + n * 16 + r;
                    if constexpr (LAYER == 1) {
                        float v = acc[m][n][j] + bias[(size_t)e * NT + col];
                        v = fmaxf(v, 0.0f);
                        H[(size_t)slot * HDIM + col] = f2bf(v);
                    } else {
                        atomicAdd(&out[(size_t)perm[slot] * ODIM + col],
                                  gate_s[slot] * acc[m][n][j]);
                    }
                }
            }
        }
    }
}

// ---------------- launch ----------------
extern "C" void kernel_launch(void* const* d_in, const int* in_sizes, int n_in,
                              void* d_out, int out_size, void* d_ws, size_t ws_size,
                              hipStream_t stream) {
    const float* x  = (const float*)d_in[0];
    const float* Wg = (const float*)d_in[1];
    const float* bg = (const float*)d_in[2];
    const float* W1 = (const float*)d_in[3];
    const float* b1 = (const float*)d_in[4];
    const float* W2 = (const float*)d_in[5];
    const float* b2 = (const float*)d_in[6];
    float* out = (float*)d_out;

    char* ws = (char*)d_ws;
    int*   cnt    = (int*)(ws + 0);
    int*   offs   = (int*)(ws + 64);
    int*   mc     = (int*)(ws + 128);
    int*   g1s    = (int*)(ws + 256);              // 480 ints
    int*   g2s    = (int*)(ws + 2304);             // 48 ints
    int*   tbl1   = (int*)(ws + 3072);             // 1536 ints
    int*   tbl2   = (int*)(ws + 10240);            // 768 ints
    int*   top_e  = (int*)(ws + 19712);
    int*   rnk    = (int*)(ws + 19712 + 16384);
    float* top_p  = (float*)(ws + 19712 + 2 * 16384);
    int*   perm   = (int*)(ws + 19712 + 3 * 16384);
    float* gate_s = (float*)(ws + 19712 + 4 * 16384);
    unsigned short* Xg  = (unsigned short*)(ws + 101632);
    unsigned short* H   = (unsigned short*)(ws + 101632 + (size_t)N_TOK * DIM * 2);
    unsigned short* W1t = (unsigned short*)(ws + 69307648ull);   // bf16 [E][H][D]
    unsigned short* W2t = (unsigned short*)(ws + 163679488ull);  // bf16 [E][O][H]
    // total ws ~246 MB (r8 proved ws_size >= 258 MB)

    moe_init<<<1, 64, 0, stream>>>(cnt);
    moe_gating<<<N_TOK / 4, 256, 0, stream>>>(x, Wg, bg, cnt, top_e, rnk, top_p);
    moe_scan<<<1, 64, 0, stream>>>(cnt, offs, mc, g1s, g2s);
    moe_fill<<<(G1GRID + G2GRID + 255) / 256, 256, 0, stream>>>(mc, g1s, g2s, tbl1, tbl2);
    moe_mkperm<<<N_TOK / 256, 256, 0, stream>>>(top_e, rnk, top_p, offs, perm, gate_s);
    moe_gather<<<N_TOK, 256, 0, stream>>>(x, perm, Xg);
    moe_initout<<<N_TOK, 256, 0, stream>>>(top_e, top_p, b2, out);

    moe_wtrans<<<dim3(HDIM / 64, DIM / 64, NE), 256, 0, stream>>>(W1, W1t, DIM, HDIM);
    moe_wtrans<<<dim3(ODIM / 64, HDIM / 64, NE), 256, 0, stream>>>(W2, W2t, HDIM, ODIM);

    moe_gemm8<1><<<G1GRID, 512, 0, stream>>>(
        Xg, W1t, b1, cnt, offs, perm, gate_s, tbl1, H, out);
    moe_gemm8<2><<<G2GRID, 512, 0, stream>>>(
        H, W2t, b2, cnt, offs, perm, gate_s, tbl2, H, out);
}

// Round 17
// 356.430 us; speedup vs baseline: 1.2882x; 1.2882x over previous
//
#include <hip/hip_runtime.h>
#include <hip/hip_bf16.h>
#include <stdint.h>

// MoE top-1. Round 17: r16's BLOCKED A-LAYOUTS with the allocation bug fixed
// (perm/gate_s now sized for the PADDED slot space 5120; r16 overflowed them,
// GEMM2 read a float as perm index -> OOB atomicAdd -> device fault).
// Xg and H stored as [slot/16][k/8][16][8] so each A-cell global_load_lds
// reads 1KB fully contiguous (8x128B segments vs 16x64B row-gather).
#define N_TOK 4096
#define DIM   768
#define NE    8
#define HDIM  7680
#define ODIM  768
#define G1GRID 2816
#define G2GRID 1344
#define KC1 96            // DIM/8 k-chunks
#define KC2 960           // HDIM/8 k-chunks
#define XB1 (KC1 * 128)   // ushorts per 16-slot block of Xg (12288)
#define XB2 (KC2 * 128)   // ushorts per 16-slot block of H (122880)
#define NSLOT 5120        // padded slot space (sum of per-expert 128-pads)

typedef __bf16 bf16x8 __attribute__((ext_vector_type(8)));
typedef float f32x4 __attribute__((ext_vector_type(4)));

__device__ __forceinline__ unsigned short f2bf(float f) {
    union { float f; unsigned u; } v; v.f = f;
    return (unsigned short)((v.u + 0x7fffu + ((v.u >> 16) & 1u)) >> 16);
}

__device__ __forceinline__ unsigned cvt_pk_bf16(float lo, float hi) {
    unsigned r;
    asm("v_cvt_pk_bf16_f32 %0, %1, %2" : "=v"(r) : "v"(lo), "v"(hi));
    return r;
}

__device__ __forceinline__ void gload_lds16(const unsigned short* g, unsigned short* l) {
    __builtin_amdgcn_global_load_lds(
        (const __attribute__((address_space(1))) unsigned int*)g,
        (__attribute__((address_space(3))) unsigned int*)l, 16, 0, 0);
}

// ---------------- gating & prep ----------------
__global__ void moe_gating(const float* __restrict__ x, const float* __restrict__ Wg,
                           const float* __restrict__ bg, int* __restrict__ cnt,
                           int* __restrict__ top_e, int* __restrict__ rnk,
                           float* __restrict__ top_p) {
    const int wid  = threadIdx.x >> 6;
    const int lane = threadIdx.x & 63;
    const int t = blockIdx.x * 4 + wid;
    double p[NE];
#pragma unroll
    for (int j = 0; j < NE; ++j) p[j] = 0.0;
    const float* xr  = x  + (size_t)t * DIM + lane * 12;
    const float* wr0 = Wg + lane * 12 * NE;
#pragma unroll
    for (int i = 0; i < 12; ++i) {
        double xv = (double)xr[i];
#pragma unroll
        for (int j = 0; j < NE; ++j) p[j] += xv * (double)wr0[i * NE + j];
    }
#pragma unroll
    for (int off = 32; off >= 1; off >>= 1)
#pragma unroll
        for (int j = 0; j < NE; ++j) p[j] += __shfl_xor(p[j], off, 64);
    if (lane == 0) {
        double l[NE];
#pragma unroll
        for (int j = 0; j < NE; ++j) l[j] = p[j] + (double)bg[j];
        int be = 0; double bl = l[0];
#pragma unroll
        for (int j = 1; j < NE; ++j) if (l[j] > bl) { bl = l[j]; be = j; }
        double s = 0.0;
#pragma unroll
        for (int j = 0; j < NE; ++j) s += exp(l[j] - bl);
        int rk = atomicAdd(&cnt[be], 1);
        top_e[t] = be; rnk[t] = rk; top_p[t] = (float)(1.0 / s);
    }
}

__global__ void moe_init(int* cnt) { if (threadIdx.x < NE) cnt[threadIdx.x] = 0; }

// offs[e] PADDED to 128-multiples (slot space <= NSLOT, 16-aligned tiles).
// mc[e] = ceil(cnt/128). Groups/XCD mapping as r9.
__global__ void moe_scan(const int* __restrict__ cnt, int* __restrict__ offs,
                         int* __restrict__ mc, int* __restrict__ g1s,
                         int* __restrict__ g2s) {
    __shared__ int smc[NE];
    int tid = threadIdx.x;
    if (tid == 0) {
        int s = 0;
        for (int e = 0; e < NE; ++e) { offs[e] = s; s += (cnt[e] + 127) & ~127; }
    }
    if (tid < NE) { smc[tid] = (cnt[tid] + 127) >> 7; mc[tid] = smc[tid]; }
    __syncthreads();
    if (tid < 8) {
        int s = 0;
        for (int j = 0; j < 60; ++j) { int p = tid + 8 * j; g1s[p] = s; s += smc[p / 60]; }
        int s2 = 0;
        for (int j = 0; j < 6; ++j)  { int p = tid + 8 * j; g2s[p] = s2; s2 += 4 * smc[p / 6]; }
    }
}

__global__ void moe_fill(const int* __restrict__ mc, const int* __restrict__ g1s,
                         const int* __restrict__ g2s, int* __restrict__ tbl1,
                         int* __restrict__ tbl2) {
    int gid = blockIdx.x * 256 + threadIdx.x;
    if (gid < G1GRID) {
        int c = gid & 7, slot = gid >> 3;
        int sel = c;
        for (int j = 0; j < 60; ++j) { int p = c + 8 * j; if (g1s[p] <= slot) sel = p; else break; }
        int e = sel / 60, n0 = sel % 60;
        int mt = slot - g1s[sel];
        tbl1[gid] = (mt < mc[e]) ? ((e << 14) | (mt << 8) | (n0 << 2)) : -1;
    } else if (gid < G1GRID + G2GRID) {
        int gg = gid - G1GRID;
        int c = gg & 7, slot = gg >> 3;
        int sel = c;
        for (int j = 0; j < 6; ++j) { int p = c + 8 * j; if (g2s[p] <= slot) sel = p; else break; }
        int e = sel / 6, n0 = sel % 6;
        int mem = slot - g2s[sel];
        int mcE = mc[e];
        int ks = mem / mcE, mt = mem - ks * mcE;
        tbl2[gg] = (mem < 4 * mcE) ? ((e << 14) | (mt << 8) | (n0 << 2) | ks) : -1;
    }
}

__global__ void moe_mkperm(const int* __restrict__ top_e, const int* __restrict__ rnk,
                           const float* __restrict__ top_p, const int* __restrict__ offs,
                           int* __restrict__ perm, float* __restrict__ gate_s) {
    int t = blockIdx.x * 256 + threadIdx.x;
    int e = top_e[t];
    int slot = offs[e] + rnk[t];     // slot < NSLOT (perm/gate_s sized NSLOT)
    perm[slot] = t;
    gate_s[slot] = top_p[t];
}

// Gather x into BLOCKED Xg: elem (slot,k) at (slot>>4)*XB1 + (k>>3)*128
// + (slot&15)*8 + (k&7). One 16B store per (token, k-chunk).
__global__ void moe_gather(const float* __restrict__ x, const int* __restrict__ top_e,
                           const int* __restrict__ rnk, const int* __restrict__ offs,
                           unsigned short* __restrict__ Xg) {
    int t = blockIdx.x;
    int slot = offs[top_e[t]] + rnk[t];
    int kc = threadIdx.x;
    if (kc < KC1) {
        const float* s8 = x + (size_t)t * DIM + kc * 8;
        union { uint4 q; unsigned short u[8]; } v;
#pragma unroll
        for (int j = 0; j < 8; ++j) v.u[j] = f2bf(s8[j]);
        *(uint4*)&Xg[(size_t)(slot >> 4) * XB1 + kc * 128 + (slot & 15) * 8] = v.q;
    }
}

__global__ void moe_initout(const int* __restrict__ top_e, const float* __restrict__ top_p,
                            const float* __restrict__ b2, float* __restrict__ out) {
    int t = blockIdx.x;
    int e = top_e[t];
    float gv = top_p[t];
    const float* b = b2 + (size_t)e * ODIM;
    float* o = out + (size_t)t * ODIM;
    for (int i = threadIdx.x; i < ODIM; i += 256) o[i] = gv * b[i];
}

// ---------------- grouped GEMM (r9 K-loop, blocked-A DMA) ----------------
// 128x128 tile, BK=32, 4 waves (2x2), acc[4][4]. A: blocked layout -> each
// gload_lds reads 1KB CONTIGUOUS (cell = 16 rows x 32 k, lane L -> L*16B).
// Pad rows read garbage; discarded by the lrow<ne epilogue guard.
// B: fp32 loads 2 iters ahead -> cvt_pk -> ds_write (r9, validated).
template<int LAYER>
__global__ __launch_bounds__(256, 3) void moe_gemm(
    const unsigned short* __restrict__ A, const float* __restrict__ B,
    const float* __restrict__ bias, const int* __restrict__ cnt,
    const int* __restrict__ offs, const int* __restrict__ perm,
    const float* __restrict__ gate_s, const int* __restrict__ tbl,
    unsigned short* __restrict__ H, float* __restrict__ out) {

    constexpr int NT    = (LAYER == 1) ? HDIM : ODIM;
    constexpr int ABLK  = (LAYER == 1) ? XB1  : XB2;   // ushorts per 16-slot block
    constexpr int KFULL = (LAYER == 1) ? DIM  : HDIM;
    constexpr int KBLK  = (LAYER == 1) ? DIM  : HDIM / 4;
    constexpr int NITER = KBLK / 32;              // 24 / 60 (even, >=4)

    const int code = tbl[blockIdx.x];
    if (code < 0) return;
    const int e  = code >> 14;
    const int mt = (code >> 8) & 63;
    const int n0 = ((code >> 2) & 63) * 128;
    const int ks = code & 3;
    const int ne = cnt[e];
    const int base = offs[e];                      // 128-aligned
    const int kbase = ks * KBLK;

    __shared__ __align__(16) unsigned short As[3][4096];
    __shared__ __align__(16) unsigned short Bs[2][4096];

    const int tid = threadIdx.x;
    const int lane = tid & 63, w = tid >> 6;
    const int wr = w >> 1, wc = w & 1;
    const int g = lane >> 4, r = lane & 15;

    // A DMA: wave w stages cells (16-row groups) 2w, 2w+1; contiguous 1KB each.
    const int ab16 = (base + mt * 128) >> 4;
    const unsigned short* aS0 = A + (size_t)(ab16 + 2 * w) * ABLK
                                  + (size_t)(kbase >> 3) * 128 + lane * 8;
    const unsigned short* aS1 = aS0 + ABLK;
    const int aD0 = (2 * w) * 512;
    const int aD1 = aD0 + 512;

    // B staging: thread owns col bn, 16 consecutive ks (half kh) [r9]
    const int bn = tid & 127;
    const int kh = tid >> 7;
    const float* bS = B + (size_t)e * KFULL * NT + (size_t)(kbase + kh * 16) * NT + n0 + bn;
    const int bD = (bn >> 4) * 512 + (kh * 2) * 128 + (bn & 15) * 8;

    f32x4 acc[4][4] = {};
    float bvA[16], bvB[16];

    unsigned short* A0 = &As[0][0];
    unsigned short* A1 = &As[1][0];
    unsigned short* A2 = &As[2][0];

#define LOADB(dst_, t_)                                                        \
    do { const float* bp_ = bS + (size_t)((t_) * 32) * NT;                     \
        _Pragma("unroll")                                                      \
        for (int i_ = 0; i_ < 16; ++i_) dst_[i_] = bp_[(size_t)i_ * NT];       \
    } while (0)

#define DMA_A(t_, abase_)                                                      \
    do { gload_lds16(aS0 + (t_) * 512, (abase_) + aD0);                        \
         gload_lds16(aS1 + (t_) * 512, (abase_) + aD1); } while (0)

#define COMMITB(src_, buf_)                                                    \
    do { uint4 q0_, q1_;                                                       \
        q0_.x = cvt_pk_bf16(src_[0],  src_[1]);  q0_.y = cvt_pk_bf16(src_[2],  src_[3]);  \
        q0_.z = cvt_pk_bf16(src_[4],  src_[5]);  q0_.w = cvt_pk_bf16(src_[6],  src_[7]);  \
        q1_.x = cvt_pk_bf16(src_[8],  src_[9]);  q1_.y = cvt_pk_bf16(src_[10], src_[11]); \
        q1_.z = cvt_pk_bf16(src_[12], src_[13]); q1_.w = cvt_pk_bf16(src_[14], src_[15]); \
        *(uint4*)&Bs[buf_][bD]       = q0_;                                    \
        *(uint4*)&Bs[buf_][bD + 128] = q1_;                                    \
    } while (0)

#define PHASE_END                                                              \
    do { asm volatile("s_waitcnt lgkmcnt(0)" ::: "memory");                    \
         __builtin_amdgcn_s_barrier();                                         \
         __builtin_amdgcn_sched_barrier(0); } while (0)

#define BODY(t_, cur_, ARD_, ADMA_, LDst_, CMsrc_, MODE_)                      \
    do {                                                                       \
        bf16x8 af_[4], bf_[4];                                                 \
        _Pragma("unroll")                                                      \
        for (int m_ = 0; m_ < 4; ++m_)                                         \
            af_[m_] = *(const bf16x8*)((ARD_) + (wr * 4 + m_) * 512 + lane * 8); \
        _Pragma("unroll")                                                      \
        for (int n_ = 0; n_ < 4; ++n_)                                         \
            bf_[n_] = *(const bf16x8*)&Bs[cur_][(wc * 4 + n_) * 512 + lane * 8]; \
        if (MODE_ == 2) DMA_A((t_) + 2, ADMA_);                                \
        if (MODE_ == 2) LOADB(LDst_, (t_) + 2);                                \
        _Pragma("unroll")                                                      \
        for (int n_ = 0; n_ < 4; ++n_)                                         \
            _Pragma("unroll")                                                  \
            for (int m_ = 0; m_ < 4; ++m_)                                     \
                acc[m_][n_] = __builtin_amdgcn_mfma_f32_16x16x32_bf16(         \
                    af_[m_], bf_[n_], acc[m_][n_], 0, 0, 0);                   \
        if (MODE_ >= 1) { COMMITB(CMsrc_, (cur_) ^ 1); PHASE_END; }            \
    } while (0)

    DMA_A(0, A0);
    LOADB(bvA, 0);
    DMA_A(1, A1);
    LOADB(bvB, 1);
    COMMITB(bvA, 0);
    PHASE_END;

#pragma unroll 1
    for (int t = 0; t + 4 <= NITER; t += 2) {
        BODY(t,     0, A0, A2, bvA, bvB, 2);
        BODY(t + 1, 1, A1, A0, bvB, bvA, 2);
        unsigned short* tr_ = A2; A2 = A1; A1 = A0; A0 = tr_;
    }
    BODY(NITER - 2, 0, A0, A2, bvA, bvB, 1);
    BODY(NITER - 1, 1, A1, A2, bvB, bvA, 0);

#undef BODY
#undef PHASE_END
#undef COMMITB
#undef DMA_A
#undef LOADB

    // epilogue: C/D layout col = lane&15 (=r), row = 4*(lane>>4) (=4g) + reg.
    // LAYER 1 writes H in BLOCKED layout (GEMM2's contiguous-DMA source).
#pragma unroll
    for (int m = 0; m < 4; ++m) {
#pragma unroll
        for (int j = 0; j < 4; ++j) {
            int lrow = mt * 128 + wr * 64 + m * 16 + g * 4 + j;
            if (lrow < ne) {
                int slot = base + lrow;
#pragma unroll
                for (int n = 0; n < 4; ++n) {
                    int col = n0 + wc * 64 + n * 16 + r;
                    if constexpr (LAYER == 1) {
                        float v = acc[m][n][j] + bias[(size_t)e * NT + col];
                        v = fmaxf(v, 0.0f);
                        H[(size_t)(slot >> 4) * XB2 + (size_t)(col >> 3) * 128
                          + (slot & 15) * 8 + (col & 7)] = f2bf(v);
                    } else {
                        atomicAdd(&out[(size_t)perm[slot] * ODIM + col],
                                  gate_s[slot] * acc[m][n][j]);
                    }
                }
            }
        }
    }
}

// ---------------- launch ----------------
extern "C" void kernel_launch(void* const* d_in, const int* in_sizes, int n_in,
                              void* d_out, int out_size, void* d_ws, size_t ws_size,
                              hipStream_t stream) {
    const float* x  = (const float*)d_in[0];
    const float* Wg = (const float*)d_in[1];
    const float* bg = (const float*)d_in[2];
    const float* W1 = (const float*)d_in[3];
    const float* b1 = (const float*)d_in[4];
    const float* W2 = (const float*)d_in[5];
    const float* b2 = (const float*)d_in[6];
    float* out = (float*)d_out;

    char* ws = (char*)d_ws;
    int*   cnt    = (int*)(ws + 0);
    int*   offs   = (int*)(ws + 64);
    int*   mc     = (int*)(ws + 128);
    int*   g1s    = (int*)(ws + 256);              // 480 ints
    int*   g2s    = (int*)(ws + 2304);             // 48 ints
    int*   tbl1   = (int*)(ws + 3072);             // 2816 ints -> ends 14336
    int*   tbl2   = (int*)(ws + 14336);            // 1344 ints -> ends 19712
    int*   top_e  = (int*)(ws + 19712);            // 4096 ints
    int*   rnk    = (int*)(ws + 19712 + 16384);    // 4096 ints
    float* top_p  = (float*)(ws + 19712 + 2 * 16384);   // 4096 f32
    int*   perm   = (int*)(ws + 68864);            // NSLOT=5120 ints -> ends 89344
    float* gate_s = (float*)(ws + 89344);          // NSLOT=5120 f32 -> ends 109824
    unsigned short* Xg = (unsigned short*)(ws + 110592);                    // 320*XB1*2 = 7.86MB
    unsigned short* H  = (unsigned short*)(ws + 110592 + 320ull * XB1 * 2); // 320*XB2*2 = 78.6MB
    // total ws ~86.6 MB

    moe_init<<<1, 64, 0, stream>>>(cnt);
    moe_gating<<<N_TOK / 4, 256, 0, stream>>>(x, Wg, bg, cnt, top_e, rnk, top_p);
    moe_scan<<<1, 64, 0, stream>>>(cnt, offs, mc, g1s, g2s);
    moe_fill<<<(G1GRID + G2GRID + 255) / 256, 256, 0, stream>>>(mc, g1s, g2s, tbl1, tbl2);
    moe_mkperm<<<N_TOK / 256, 256, 0, stream>>>(top_e, rnk, top_p, offs, perm, gate_s);
    moe_gather<<<N_TOK, 128, 0, stream>>>(x, top_e, rnk, offs, Xg);
    moe_initout<<<N_TOK, 256, 0, stream>>>(top_e, top_p, b2, out);

    moe_gemm<1><<<G1GRID, 256, 0, stream>>>(Xg, W1, b1, cnt, offs, perm, gate_s, tbl1, H, out);
    moe_gemm<2><<<G2GRID, 256, 0, stream>>>(H, W2, b2, cnt, offs, perm, gate_s, tbl2, H, out);
}